// Round 6
// baseline (83.029 us; speedup 1.0000x reference)
//
#include <hip/hip_runtime.h>
#include <hip/hip_bf16.h>

typedef __bf16 bf16x8 __attribute__((ext_vector_type(8)));
typedef __bf16 bf16x4 __attribute__((ext_vector_type(4)));
typedef float  f32x4  __attribute__((ext_vector_type(4)));

constexpr int kD  = 512;
constexpr int kBD = 64;
constexpr int kN  = 4096;
constexpr int kB  = 8;

constexpr int BROWS = 32;   // rows per block -> grid 1024

// ---- raw VMEM: issue order and waits are OURS, not the compiler's ----
__device__ __forceinline__ f32x4 gld_f4(const float* p) {
    f32x4 r;
    asm volatile("global_load_dwordx4 %0, %1, off" : "=v"(r) : "v"(p));
    return r;
}
__device__ __forceinline__ bf16x8 gld_w8(const __bf16* p) {
    bf16x8 r;
    asm volatile("global_load_dwordx4 %0, %1, off" : "=v"(r) : "v"(p));
    return r;
}
__device__ __forceinline__ bf16x4 cvt4(f32x4 a) {
    bf16x4 r;
    r[0] = (__bf16)a[0]; r[1] = (__bf16)a[1];
    r[2] = (__bf16)a[2]; r[3] = (__bf16)a[3];
    return r;
}

// Prep: Wbk/Wbv fp32 -> bf16 ws images (blocks 0..31); block 32 zeroes S.
__global__ __launch_bounds__(256)
void lbm_prep(const float* __restrict__ Wbk, const float* __restrict__ Wbv,
              __bf16* __restrict__ wsk, __bf16* __restrict__ wsv,
              float* __restrict__ S)
{
    const int bid = blockIdx.x, t = threadIdx.x;
    if (bid < 32) {
        int i = (bid * 256 + t) * 4;
        float4 a = *(const float4*)(Wbk + i);
        float4 b = *(const float4*)(Wbv + i);
        bf16x4 ka, vb;
        ka[0]=(__bf16)a.x; ka[1]=(__bf16)a.y; ka[2]=(__bf16)a.z; ka[3]=(__bf16)a.w;
        vb[0]=(__bf16)b.x; vb[1]=(__bf16)b.y; vb[2]=(__bf16)b.z; vb[3]=(__bf16)b.w;
        *(bf16x4*)(wsk + i) = ka;
        *(bf16x4*)(wsv + i) = vb;
    } else {
        S[t * 2] = 0.f; S[t * 2 + 1] = 0.f;
    }
}

// S[b,j] = sum_n (keys[b,n,:].Wbk[j,:] + bbk[j]) * (values[b,n,:].Wbv[j,:] + bbv[j])
//
// Reg-staged streaming (m13-proven HBM path): per phase each wave loads one
// contiguous 1KB run per row (copy-like instruction footprint), cvt -> bf16,
// XOR-swizzled ds_write (conflict-free write AND read). One s_barrier/phase,
// counted vmcnt in issue order [W x16, D x8] so weight waits never drain data.
__global__ __launch_bounds__(256, 3)
void lbm_bind(const float* __restrict__ keys, const float* __restrict__ values,
              const __bf16* __restrict__ wsk, const __bf16* __restrict__ wsv,
              const float* __restrict__ bbk,  const float* __restrict__ bbv,
              float* __restrict__ S)
{
    __shared__ __bf16 lds[2][2][16 * 256];   // [buf][K/V][16 rows x 256 f] bf16 = 32 KB

    const int tid = threadIdx.x;
    const int wv  = tid >> 6;
    const int ln  = tid & 63;
    const int l15 = ln & 15;
    const int lhi = ln >> 4;
    const int jrow = wv * 16 + l15;          // weight row (j) for B-operand
    const int blockRow0 = blockIdx.x * BROWS;

    const float bk = bbk[jrow];
    const float bv = bbv[jrow];

    // write indices (bf16 elems): slot k writes row wr = wv+4k, floats [ln*4, ln*4+4)
    // swizzle: 16B-granule g16 = ln>>1 -> g16 ^ (wr&7); half-granule = ln&1
    int widx[4];
    #pragma unroll
    for (int k = 0; k < 4; ++k) {
        int wr = wv + 4 * k;
        widx[k] = wr * 256 + (((ln >> 1) ^ (wr & 7)) << 3) + ((ln & 1) << 2);
    }

    f32x4 dk[4], dv[4];

    // ---- prologue: D(0) = chunk0/half0 ----
    #pragma unroll
    for (int k = 0; k < 4; ++k) {
        const float* pk = keys   + (size_t)(blockRow0 + wv + 4 * k) * kD + ln * 4;
        const float* pv = values + (size_t)(blockRow0 + wv + 4 * k) * kD + ln * 4;
        dk[k] = gld_f4(pk);
        dv[k] = gld_f4(pv);
    }
    asm volatile("s_waitcnt vmcnt(0)" ::: "memory");
    __builtin_amdgcn_sched_barrier(0);
    #pragma unroll
    for (int k = 0; k < 4; ++k) {
        *(bf16x4*)&lds[0][0][widx[k]] = cvt4(dk[k]);
        *(bf16x4*)&lds[0][1][widx[k]] = cvt4(dv[k]);
    }
    asm volatile("s_waitcnt lgkmcnt(0)" ::: "memory");
    __builtin_amdgcn_s_barrier();
    __builtin_amdgcn_sched_barrier(0);

    float sreg = 0.0f;
    f32x4 kacc = {0.f, 0.f, 0.f, 0.f};
    f32x4 vacc = {0.f, 0.f, 0.f, 0.f};

    // phases: p -> chunk c = p>>1 (16 rows), half h = p&1 (256-float d-range)
    #pragma unroll
    for (int p = 0; p < 4; ++p) {
        const int c = p >> 1, h = p & 1, buf = p & 1;

        // ---- issue W(p): 16 frag loads (L2-hot bf16 images) ----
        bf16x8 wk[8], wvv[8];
        #pragma unroll
        for (int s = 0; s < 8; ++s) {
            wk[s]  = gld_w8(wsk + jrow * kD + (h * 8 + s) * 32 + lhi * 8);
            wvv[s] = gld_w8(wsv + jrow * kD + (h * 8 + s) * 32 + lhi * 8);
        }
        __builtin_amdgcn_sched_barrier(0);

        // ---- issue D(p+1): 8 contiguous-run data loads ----
        if (p < 3) {
            const int nc = (p + 1) >> 1, nh = (p + 1) & 1;
            #pragma unroll
            for (int k = 0; k < 4; ++k) {
                const float* pk = keys   + (size_t)(blockRow0 + nc * 16 + wv + 4 * k) * kD + nh * 256 + ln * 4;
                const float* pv = values + (size_t)(blockRow0 + nc * 16 + wv + 4 * k) * kD + nh * 256 + ln * 4;
                dk[k] = gld_f4(pk);
                dv[k] = gld_f4(pv);
            }
            asm volatile("s_waitcnt vmcnt(8)" ::: "memory");   // weights done, data in flight
        } else {
            asm volatile("s_waitcnt vmcnt(0)" ::: "memory");
        }
        __builtin_amdgcn_sched_barrier(0);

        // ---- compute: 8 d-steps x (K,V) MFMA from bf16 LDS ----
        #pragma unroll
        for (int s = 0; s < 8; ++s) {
            const int ridx = l15 * 256 + ((((s << 2) + lhi) ^ (l15 & 7)) << 3);
            bf16x8 ak = *(const bf16x8*)&lds[buf][0][ridx];
            bf16x8 av = *(const bf16x8*)&lds[buf][1][ridx];
            kacc = __builtin_amdgcn_mfma_f32_16x16x32_bf16(ak, wk[s],  kacc, 0, 0, 0);
            vacc = __builtin_amdgcn_mfma_f32_16x16x32_bf16(av, wvv[s], vacc, 0, 0, 0);
        }

        if (h == 1) {   // chunk complete: combine K/V projections
            #pragma unroll
            for (int i = 0; i < 4; ++i)
                sreg += (kacc[i] + bk) * (vacc[i] + bv);
            #pragma unroll
            for (int i = 0; i < 4; ++i) { kacc[i] = 0.f; vacc[i] = 0.f; }
        }

        // ---- write D(p+1) into the other buffer; single barrier per phase ----
        if (p < 3) {
            __builtin_amdgcn_sched_barrier(0);
            asm volatile("s_waitcnt vmcnt(0)" ::: "memory");
            __builtin_amdgcn_sched_barrier(0);
            const int nbuf = (p + 1) & 1;
            #pragma unroll
            for (int k = 0; k < 4; ++k) {
                *(bf16x4*)&lds[nbuf][0][widx[k]] = cvt4(dk[k]);
                *(bf16x4*)&lds[nbuf][1][widx[k]] = cvt4(dv[k]);
            }
            asm volatile("s_waitcnt lgkmcnt(0)" ::: "memory");
            __builtin_amdgcn_s_barrier();
            __builtin_amdgcn_sched_barrier(0);
        }
    }

    // reduce over the 4 row-groups (C/D rows live in lanes ^16, ^32)
    sreg += __shfl_xor(sreg, 16);
    sreg += __shfl_xor(sreg, 32);
    if (lhi == 0) {
        int b = blockRow0 / kN;
        atomicAdd(&S[b * kBD + jrow], sreg);
    }
}

// Fused tail: 64 blocks; each block redundantly computes S->Bsum->ms->ext->LN
// for its batch b (tiny), then produces its 64-wide slice of out = normed.Wo^T + bo.
__global__ __launch_bounds__(256)
void lbm_tail(const float* __restrict__ S,    const float* __restrict__ query,
              const float* __restrict__ Wbc,  const float* __restrict__ bbc,
              const float* __restrict__ Wuq,  const float* __restrict__ buq,
              const float* __restrict__ Wue,  const float* __restrict__ bue,
              const float* __restrict__ ln_g, const float* __restrict__ ln_b,
              const float* __restrict__ Wo,   const float* __restrict__ bo,
              float* __restrict__ out)
{
    const int b = blockIdx.x >> 3;
    const int s = blockIdx.x & 7;          // 64-wide output slice
    const int t = threadIdx.x;

    __shared__ float shS[kBD];
    __shared__ float shB[kD];
    __shared__ float shMs[kBD];
    __shared__ float shN[kD];
    __shared__ float redT[4][kBD];
    __shared__ float redQ[4][kBD];
    __shared__ float redLN[8];
    __shared__ float s_mu, s_rs;

    if (t < kBD) shS[t] = S[b * kBD + t];
    __syncthreads();

    // Bsum[d] = sum_j S[j]*Wbc[d,j] + n*bbc[d]
    for (int d = t; d < kD; d += 256) {
        const float4* wr = (const float4*)(Wbc + d * kBD);
        float acc = 0.f;
        #pragma unroll
        for (int q4 = 0; q4 < 16; ++q4) {
            float4 w = wr[q4];
            acc += w.x * shS[q4*4+0] + w.y * shS[q4*4+1]
                 + w.z * shS[q4*4+2] + w.w * shS[q4*4+3];
        }
        shB[d] = acc + (float)kN * bbc[d];
    }
    __syncthreads();

    // t[jj] = Bsum.Wuq[jj,:] + n*buq ; q[jj] = query.Wuq[jj,:] + buq ; ms = q*t
    {
        const int jj = t & 63, qq = t >> 6;
        const float4* wr = (const float4*)(Wuq + jj * kD + qq * 128);
        const float4* qr = (const float4*)(query + b * kD + qq * 128);
        const float4* br = (const float4*)(shB + qq * 128);
        float at = 0.f, aq = 0.f;
        #pragma unroll
        for (int i = 0; i < 32; ++i) {
            float4 w = wr[i]; float4 bb = br[i]; float4 qv = qr[i];
            at += w.x*bb.x + w.y*bb.y + w.z*bb.z + w.w*bb.w;
            aq += w.x*qv.x + w.y*qv.y + w.z*qv.z + w.w*qv.w;
        }
        redT[qq][jj] = at; redQ[qq][jj] = aq;
    }
    __syncthreads();
    if (t < kBD) {
        float tv = redT[0][t] + redT[1][t] + redT[2][t] + redT[3][t] + (float)kN * buq[t];
        float qv = redQ[0][t] + redQ[1][t] + redQ[2][t] + redQ[3][t] + buq[t];
        shMs[t] = tv * qv;
    }
    __syncthreads();

    // ext[d] -> ret -> LN stats
    float lsum = 0.f, lsq = 0.f;
    for (int d = t; d < kD; d += 256) {
        const float4* wr = (const float4*)(Wue + d * kBD);
        float acc = 0.f;
        #pragma unroll
        for (int q4 = 0; q4 < 16; ++q4) {
            float4 w = wr[q4];
            acc += w.x * shMs[q4*4+0] + w.y * shMs[q4*4+1]
                 + w.z * shMs[q4*4+2] + w.w * shMs[q4*4+3];
        }
        float ret = (acc + (float)kN * bue[d]) * (1.0f / 64.0f);
        shN[d] = ret;
        lsum += ret; lsq += ret * ret;
    }
    #pragma unroll
    for (int m = 1; m < 64; m <<= 1) {
        lsum += __shfl_xor(lsum, m);
        lsq  += __shfl_xor(lsq, m);
    }
    if ((t & 63) == 0) { redLN[t >> 6] = lsum; redLN[4 + (t >> 6)] = lsq; }
    __syncthreads();
    if (t == 0) {
        float s0 = redLN[0] + redLN[1] + redLN[2] + redLN[3];
        float s1 = redLN[4] + redLN[5] + redLN[6] + redLN[7];
        float mu = s0 / (float)kD;
        float var = s1 / (float)kD - mu * mu;
        s_mu = mu;
        s_rs = rsqrtf(var + 1e-5f);
    }
    __syncthreads();
    {
        float mu = s_mu, rs = s_rs;
        for (int d = t; d < kD; d += 256)
            shN[d] = (shN[d] - mu) * rs * ln_g[d] + ln_b[d];
    }
    __syncthreads();

    // out slice: d = s*64 + t/4, quarter q = t&3 over the 512-dot
    {
        const int d = s * 64 + (t >> 2);
        const int q = t & 3;
        const float4* wr = (const float4*)(Wo + d * kD + q * 128);
        const float4* nr = (const float4*)(shN + q * 128);
        float acc = 0.f;
        #pragma unroll
        for (int i = 0; i < 32; ++i) {
            float4 w = wr[i]; float4 nv = nr[i];
            acc += w.x*nv.x + w.y*nv.y + w.z*nv.z + w.w*nv.w;
        }
        acc += __shfl_xor(acc, 1);
        acc += __shfl_xor(acc, 2);
        if (q == 0) out[b * kD + d] = acc + bo[d];
    }
}

extern "C" void kernel_launch(void* const* d_in, const int* in_sizes, int n_in,
                              void* d_out, int out_size, void* d_ws, size_t ws_size,
                              hipStream_t stream) {
    const float* keys   = (const float*)d_in[0];
    const float* values = (const float*)d_in[1];
    const float* query  = (const float*)d_in[2];
    const float* Wbk    = (const float*)d_in[3];
    const float* bbk    = (const float*)d_in[4];
    const float* Wbv    = (const float*)d_in[5];
    const float* bbv    = (const float*)d_in[6];
    const float* Wbc    = (const float*)d_in[7];
    const float* bbc    = (const float*)d_in[8];
    const float* Wuq    = (const float*)d_in[9];
    const float* buq    = (const float*)d_in[10];
    const float* Wue    = (const float*)d_in[11];
    const float* bue    = (const float*)d_in[12];
    const float* ln_g   = (const float*)d_in[13];
    const float* ln_b   = (const float*)d_in[14];
    const float* Wo     = (const float*)d_in[15];
    const float* bo     = (const float*)d_in[16];

    // ws layout: S[8][64] f32 (2 KB), wsk[64*512] bf16 (64 KB), wsv[64*512] bf16 (64 KB)
    float*  Sacc = (float*)d_ws;
    __bf16* wsk  = (__bf16*)((char*)d_ws + 2048);
    __bf16* wsv  = wsk + kBD * kD;
    float*  out  = (float*)d_out;

    lbm_prep<<<dim3(33), dim3(256), 0, stream>>>(Wbk, Wbv, wsk, wsv, Sacc);

    const int nblocks = (kB * kN) / BROWS;   // 1024
    lbm_bind<<<dim3(nblocks), dim3(256), 0, stream>>>(keys, values, wsk, wsv, bbk, bbv, Sacc);
    lbm_tail<<<dim3(kB * 8), dim3(256), 0, stream>>>(Sacc, query, Wbc, bbc, Wuq, buq,
                                                     Wue, bue, ln_g, ln_b, Wo, bo, out);
}

// Round 7
// 73.971 us; speedup vs baseline: 1.1225x; 1.1225x over previous
//
#include <hip/hip_runtime.h>
#include <hip/hip_bf16.h>

typedef __bf16 bf16x8 __attribute__((ext_vector_type(8)));
typedef __bf16 bf16x4 __attribute__((ext_vector_type(4)));
typedef float  f32x4  __attribute__((ext_vector_type(4)));

constexpr int kD  = 512;
constexpr int kBD = 64;
constexpr int kN  = 4096;
constexpr int kB  = 8;

constexpr int BROWS = 32;   // rows per block -> grid 1024 (all resident, 4 blocks/CU)
constexpr int NPH   = 8;    // d-units of 64 floats (staged 32r x 64d x {K,V} = 16 KB/phase)

typedef const __attribute__((address_space(1))) void* gas_t;
typedef __attribute__((address_space(3))) void*       las_t;

static __device__ __forceinline__ void gload16(const void* g, void* l) {
    __builtin_amdgcn_global_load_lds((gas_t)g, (las_t)l, 16, 0, 0);
}

__device__ __forceinline__ bf16x8 cvt8(float4 a, float4 b) {
    bf16x8 r;
    r[0] = (__bf16)a.x; r[1] = (__bf16)a.y; r[2] = (__bf16)a.z; r[3] = (__bf16)a.w;
    r[4] = (__bf16)b.x; r[5] = (__bf16)b.y; r[6] = (__bf16)b.z; r[7] = (__bf16)b.w;
    return r;
}

// Prep: Wbk/Wbv fp32 -> bf16 ws images (blocks 0..31); block 32 zeroes S.
__global__ __launch_bounds__(256)
void lbm_prep(const float* __restrict__ Wbk, const float* __restrict__ Wbv,
              __bf16* __restrict__ wsk, __bf16* __restrict__ wsv,
              float* __restrict__ S)
{
    const int bid = blockIdx.x, t = threadIdx.x;
    if (bid < 32) {
        int i = (bid * 256 + t) * 4;
        float4 a = *(const float4*)(Wbk + i);
        float4 b = *(const float4*)(Wbv + i);
        bf16x4 ka, vb;
        ka[0]=(__bf16)a.x; ka[1]=(__bf16)a.y; ka[2]=(__bf16)a.z; ka[3]=(__bf16)a.w;
        vb[0]=(__bf16)b.x; vb[1]=(__bf16)b.y; vb[2]=(__bf16)b.z; vb[3]=(__bf16)b.w;
        *(bf16x4*)(wsk + i) = ka;
        *(bf16x4*)(wsv + i) = vb;
    } else {
        S[t * 2] = 0.f; S[t * 2 + 1] = 0.f;
    }
}

// S[b,j] = sum_n (keys[b,n,:].Wbk[j,:] + bbk[j]) * (values[b,n,:].Wbv[j,:] + bbv[j])
//
// Max-TLP variant of the R5 core: 512-thread blocks (8 waves = 2 row-chunks x
// 4 j-tiles sharing one staged 32r x 64d unit), 32 KB LDS dbuf, grid 1024 ->
// 4 blocks/CU = 32 waves/CU. global_load_lds staging, linear LDS dest
// (granule = tid), XOR-pre-swizzled source granules (conflict-light reads).
// Weight B-fragments stream from the L2-hot bf16 ws image every phase.
__global__ __launch_bounds__(512, 8)
void lbm_bind(const float* __restrict__ keys, const float* __restrict__ values,
              const __bf16* __restrict__ wsk, const __bf16* __restrict__ wsv,
              const float* __restrict__ bbk,  const float* __restrict__ bbv,
              float* __restrict__ S)
{
    __shared__ float lds[2][2][BROWS * 64];   // [buf][K/V][32 rows x 64 d] = 32 KB

    const int tid = threadIdx.x;
    const int w   = tid >> 6;
    const int ln  = tid & 63;
    const int l15 = ln & 15;
    const int lhi = ln >> 4;
    const int jt  = w & 3;             // j-tile of this wave
    const int ch  = w >> 2;            // row-chunk of this wave (0/1)
    const int jrow = jt * 16 + l15;    // weight row (j) for B-operand
    const int rowA = ch * 16 + l15;    // A-frag row within the staged unit
    const int sw   = l15 & 7;          // read-side XOR swizzle key (== rowA & 7)

    const int blockRow0 = blockIdx.x * BROWS;

    // staging: thread t owns dest granule t (linear -- gload_lds requirement);
    // source granule column is XOR-swizzled within each 8-granule (128 B) group.
    const int sr  = tid >> 4;          // row 0..31
    const int sc  = tid & 15;          // dest granule col 0..15
    const int ssc = sc ^ (sr & 7);     // source granule col
    const float* skey = keys   + (size_t)(blockRow0 + sr) * kD + ssc * 4;
    const float* sval = values + (size_t)(blockRow0 + sr) * kD + ssc * 4;

#define STAGE(p)                                                   \
    {                                                              \
        gload16(skey + (p) * 64, &lds[(p) & 1][0][tid * 4]);       \
        gload16(sval + (p) * 64, &lds[(p) & 1][1][tid * 4]);       \
    }

    STAGE(0)
    const float bk = bbk[jrow];
    const float bv = bbv[jrow];
    __syncthreads();   // unit 0 resident

    f32x4 kacc = {0.f, 0.f, 0.f, 0.f};
    f32x4 vacc = {0.f, 0.f, 0.f, 0.f};

    #pragma unroll
    for (int p = 0; p < NPH; ++p) {
        if (p + 1 < NPH) STAGE(p + 1)          // next unit in flight under compute

        const int buf = p & 1;
        const float* bK = &lds[buf][0][0];
        const float* bV = &lds[buf][1][0];

        // weight fragments for this d-unit (L2-hot bf16 image), both d-steps
        bf16x8 wk0 = *(const bf16x8*)(wsk + jrow * kD + p * 64 + lhi * 8);
        bf16x8 wk1 = *(const bf16x8*)(wsk + jrow * kD + p * 64 + 32 + lhi * 8);
        bf16x8 wv0 = *(const bf16x8*)(wsv + jrow * kD + p * 64 + lhi * 8);
        bf16x8 wv1 = *(const bf16x8*)(wsv + jrow * kD + p * 64 + 32 + lhi * 8);

        // A-frag granules: gc = d0*8 + lhi*2, de-swizzled with ^sw
        const int gc0 = lhi * 2;
        const int o00 = rowA * 64 + ((gc0 ^ sw) << 2);
        const int o01 = rowA * 64 + (((gc0 + 1) ^ sw) << 2);
        const int gc1 = 8 + lhi * 2;
        const int o10 = rowA * 64 + ((gc1 ^ sw) << 2);
        const int o11 = rowA * 64 + (((gc1 + 1) ^ sw) << 2);

        float4 a, b;
        a = *(const float4*)&bK[o00]; b = *(const float4*)&bK[o01];
        kacc = __builtin_amdgcn_mfma_f32_16x16x32_bf16(cvt8(a, b), wk0, kacc, 0, 0, 0);
        a = *(const float4*)&bV[o00]; b = *(const float4*)&bV[o01];
        vacc = __builtin_amdgcn_mfma_f32_16x16x32_bf16(cvt8(a, b), wv0, vacc, 0, 0, 0);
        a = *(const float4*)&bK[o10]; b = *(const float4*)&bK[o11];
        kacc = __builtin_amdgcn_mfma_f32_16x16x32_bf16(cvt8(a, b), wk1, kacc, 0, 0, 0);
        a = *(const float4*)&bV[o10]; b = *(const float4*)&bV[o11];
        vacc = __builtin_amdgcn_mfma_f32_16x16x32_bf16(cvt8(a, b), wv1, vacc, 0, 0, 0);

        __syncthreads();   // staged p+1 visible; readers done before buf reuse
    }
#undef STAGE

    // combine projections for this wave's 16-row chunk
    float sreg = 0.0f;
    #pragma unroll
    for (int i = 0; i < 4; ++i)
        sreg += (kacc[i] + bk) * (vacc[i] + bv);

    // reduce over the 4 row-groups (C/D rows live in lanes ^16, ^32)
    sreg += __shfl_xor(sreg, 16);
    sreg += __shfl_xor(sreg, 32);
    if (lhi == 0) {
        int bidx = blockRow0 >> 12;   // / kN
        atomicAdd(&S[bidx * kBD + jrow], sreg);
    }
}

// Fused tail: 64 blocks; each block redundantly computes S->Bsum->ms->ext->LN
// for its batch b (tiny), then produces its 64-wide slice of out = normed.Wo^T + bo.
__global__ __launch_bounds__(256)
void lbm_tail(const float* __restrict__ S,    const float* __restrict__ query,
              const float* __restrict__ Wbc,  const float* __restrict__ bbc,
              const float* __restrict__ Wuq,  const float* __restrict__ buq,
              const float* __restrict__ Wue,  const float* __restrict__ bue,
              const float* __restrict__ ln_g, const float* __restrict__ ln_b,
              const float* __restrict__ Wo,   const float* __restrict__ bo,
              float* __restrict__ out)
{
    const int b = blockIdx.x >> 3;
    const int s = blockIdx.x & 7;          // 64-wide output slice
    const int t = threadIdx.x;

    __shared__ float shS[kBD];
    __shared__ float shB[kD];
    __shared__ float shMs[kBD];
    __shared__ float shN[kD];
    __shared__ float redT[4][kBD];
    __shared__ float redQ[4][kBD];
    __shared__ float redLN[8];
    __shared__ float s_mu, s_rs;

    if (t < kBD) shS[t] = S[b * kBD + t];
    __syncthreads();

    // Bsum[d] = sum_j S[j]*Wbc[d,j] + n*bbc[d]
    for (int d = t; d < kD; d += 256) {
        const float4* wr = (const float4*)(Wbc + d * kBD);
        float acc = 0.f;
        #pragma unroll
        for (int q4 = 0; q4 < 16; ++q4) {
            float4 w = wr[q4];
            acc += w.x * shS[q4*4+0] + w.y * shS[q4*4+1]
                 + w.z * shS[q4*4+2] + w.w * shS[q4*4+3];
        }
        shB[d] = acc + (float)kN * bbc[d];
    }
    __syncthreads();

    // t[jj] = Bsum.Wuq[jj,:] + n*buq ; q[jj] = query.Wuq[jj,:] + buq ; ms = q*t
    {
        const int jj = t & 63, qq = t >> 6;
        const float4* wr = (const float4*)(Wuq + jj * kD + qq * 128);
        const float4* qr = (const float4*)(query + b * kD + qq * 128);
        const float4* br = (const float4*)(shB + qq * 128);
        float at = 0.f, aq = 0.f;
        #pragma unroll
        for (int i = 0; i < 32; ++i) {
            float4 w = wr[i]; float4 bb = br[i]; float4 qv = qr[i];
            at += w.x*bb.x + w.y*bb.y + w.z*bb.z + w.w*bb.w;
            aq += w.x*qv.x + w.y*qv.y + w.z*qv.z + w.w*qv.w;
        }
        redT[qq][jj] = at; redQ[qq][jj] = aq;
    }
    __syncthreads();
    if (t < kBD) {
        float tv = redT[0][t] + redT[1][t] + redT[2][t] + redT[3][t] + (float)kN * buq[t];
        float qv = redQ[0][t] + redQ[1][t] + redQ[2][t] + redQ[3][t] + buq[t];
        shMs[t] = tv * qv;
    }
    __syncthreads();

    // ext[d] -> ret -> LN stats
    float lsum = 0.f, lsq = 0.f;
    for (int d = t; d < kD; d += 256) {
        const float4* wr = (const float4*)(Wue + d * kBD);
        float acc = 0.f;
        #pragma unroll
        for (int q4 = 0; q4 < 16; ++q4) {
            float4 w = wr[q4];
            acc += w.x * shMs[q4*4+0] + w.y * shMs[q4*4+1]
                 + w.z * shMs[q4*4+2] + w.w * shMs[q4*4+3];
        }
        float ret = (acc + (float)kN * bue[d]) * (1.0f / 64.0f);
        shN[d] = ret;
        lsum += ret; lsq += ret * ret;
    }
    #pragma unroll
    for (int m = 1; m < 64; m <<= 1) {
        lsum += __shfl_xor(lsum, m);
        lsq  += __shfl_xor(lsq, m);
    }
    if ((t & 63) == 0) { redLN[t >> 6] = lsum; redLN[4 + (t >> 6)] = lsq; }
    __syncthreads();
    if (t == 0) {
        float s0 = redLN[0] + redLN[1] + redLN[2] + redLN[3];
        float s1 = redLN[4] + redLN[5] + redLN[6] + redLN[7];
        float mu = s0 / (float)kD;
        float var = s1 / (float)kD - mu * mu;
        s_mu = mu;
        s_rs = rsqrtf(var + 1e-5f);
    }
    __syncthreads();
    {
        float mu = s_mu, rs = s_rs;
        for (int d = t; d < kD; d += 256)
            shN[d] = (shN[d] - mu) * rs * ln_g[d] + ln_b[d];
    }
    __syncthreads();

    // out slice: d = s*64 + t/4, quarter q = t&3 over the 512-dot
    {
        const int d = s * 64 + (t >> 2);
        const int q = t & 3;
        const float4* wr = (const float4*)(Wo + d * kD + q * 128);
        const float4* nr = (const float4*)(shN + q * 128);
        float acc = 0.f;
        #pragma unroll
        for (int i = 0; i < 32; ++i) {
            float4 w = wr[i]; float4 nv = nr[i];
            acc += w.x*nv.x + w.y*nv.y + w.z*nv.z + w.w*nv.w;
        }
        acc += __shfl_xor(acc, 1);
        acc += __shfl_xor(acc, 2);
        if (q == 0) out[b * kD + d] = acc + bo[d];
    }
}

extern "C" void kernel_launch(void* const* d_in, const int* in_sizes, int n_in,
                              void* d_out, int out_size, void* d_ws, size_t ws_size,
                              hipStream_t stream) {
    const float* keys   = (const float*)d_in[0];
    const float* values = (const float*)d_in[1];
    const float* query  = (const float*)d_in[2];
    const float* Wbk    = (const float*)d_in[3];
    const float* bbk    = (const float*)d_in[4];
    const float* Wbv    = (const float*)d_in[5];
    const float* bbv    = (const float*)d_in[6];
    const float* Wbc    = (const float*)d_in[7];
    const float* bbc    = (const float*)d_in[8];
    const float* Wuq    = (const float*)d_in[9];
    const float* buq    = (const float*)d_in[10];
    const float* Wue    = (const float*)d_in[11];
    const float* bue    = (const float*)d_in[12];
    const float* ln_g   = (const float*)d_in[13];
    const float* ln_b   = (const float*)d_in[14];
    const float* Wo     = (const float*)d_in[15];
    const float* bo     = (const float*)d_in[16];

    // ws layout: S[8][64] f32 (2 KB), wsk[64*512] bf16 (64 KB), wsv[64*512] bf16 (64 KB)
    float*  Sacc = (float*)d_ws;
    __bf16* wsk  = (__bf16*)((char*)d_ws + 2048);
    __bf16* wsv  = wsk + kBD * kD;
    float*  out  = (float*)d_out;

    lbm_prep<<<dim3(33), dim3(256), 0, stream>>>(Wbk, Wbv, wsk, wsv, Sacc);

    const int nblocks = (kB * kN) / BROWS;   // 1024 blocks x 512 threads, all resident
    lbm_bind<<<dim3(nblocks), dim3(512), 0, stream>>>(keys, values, wsk, wsv, bbk, bbv, Sacc);
    lbm_tail<<<dim3(kB * 8), dim3(256), 0, stream>>>(Sacc, query, Wbc, bbc, Wuq, buq,
                                                     Wue, bue, ln_g, ln_b, Wo, bo, out);
}